// Round 1
// baseline (48112.476 us; speedup 1.0000x reference)
//
#include <hip/hip_runtime.h>
#include <hip/hip_bf16.h>
#include <math.h>

// Problem constants (from reference)
constexpr int L = 4, B = 4, T = 2048, C = 1024, H = 16, F = 4096, V = 32000;
constexpr int D = C / H;        // 64
constexpr int M = B * T;        // 8192 token rows
constexpr float EPS = 1e-5f;

// ---------------------------------------------------------------------------
// Embedding: x[b,t,:] = tok_emb[idx[b,t],:] + pos_emb[t,:]
// One float4 per thread.
// ---------------------------------------------------------------------------
__global__ __launch_bounds__(256) void embed_kernel(
    const int* __restrict__ idx, const float* __restrict__ tok,
    const float* __restrict__ pos, float* __restrict__ x) {
  size_t e4 = ((size_t)blockIdx.x * 256 + threadIdx.x) * 4;  // float index
  int row = (int)(e4 / C);
  int c   = (int)(e4 % C);
  int t   = row % T;
  int tokid = idx[row];
  const float4 tv = *(const float4*)(tok + (size_t)tokid * C + c);
  const float4 pv = *(const float4*)(pos + (size_t)t * C + c);
  float4 o;
  o.x = tv.x + pv.x; o.y = tv.y + pv.y; o.z = tv.z + pv.z; o.w = tv.w + pv.w;
  *(float4*)(x + e4) = o;
}

// ---------------------------------------------------------------------------
// LayerNorm: one 256-thread block per row (C=1024 -> 4 elems/thread).
// in-row = blockIdx.x*rowMul + rowAdd ; out-row = blockIdx.x (compact).
// ---------------------------------------------------------------------------
__global__ __launch_bounds__(256) void ln_kernel(
    const float* __restrict__ xin, const float* __restrict__ g,
    const float* __restrict__ bta, float* __restrict__ out,
    int rowMul, int rowAdd) {
  int row_in = blockIdx.x * rowMul + rowAdd;
  const float* xr = xin + (size_t)row_in * C;
  int c = threadIdx.x * 4;
  float4 xv = *(const float4*)(xr + c);
  float s  = xv.x + xv.y + xv.z + xv.w;
  float ss = xv.x * xv.x + xv.y * xv.y + xv.z * xv.z + xv.w * xv.w;
  // intra-wave butterfly
  #pragma unroll
  for (int off = 32; off > 0; off >>= 1) {
    s  += __shfl_xor(s, off);
    ss += __shfl_xor(ss, off);
  }
  __shared__ float sh[8];
  int wid = threadIdx.x >> 6, lane = threadIdx.x & 63;
  if (lane == 0) { sh[wid * 2] = s; sh[wid * 2 + 1] = ss; }
  __syncthreads();
  s  = sh[0] + sh[2] + sh[4] + sh[6];
  ss = sh[1] + sh[3] + sh[5] + sh[7];
  float mean = s / C;
  float var  = ss / C - mean * mean;
  float inv  = rsqrtf(var + EPS);
  float4 gv = *(const float4*)(g + c);
  float4 bv = *(const float4*)(bta + c);
  float4 o;
  o.x = (xv.x - mean) * inv * gv.x + bv.x;
  o.y = (xv.y - mean) * inv * gv.y + bv.y;
  o.z = (xv.z - mean) * inv * gv.z + bv.z;
  o.w = (xv.w - mean) * inv * gv.w + bv.w;
  *(float4*)(out + (size_t)blockIdx.x * C + c) = o;
}

// ---------------------------------------------------------------------------
// fp32 tiled GEMM: Cout[M x N] = A[M x K] @ Bw[K x N] + bias (+resid) (relu?)
// 64x64 tile, 256 threads (16x16), 4x4 acc per thread, BK=16.
// ---------------------------------------------------------------------------
__global__ __launch_bounds__(256) void gemm_kernel(
    const float* __restrict__ A, const float* __restrict__ Bw,
    const float* __restrict__ bias, const float* __restrict__ resid,
    float* __restrict__ Cout, int N, int K, int relu) {
  constexpr int BK = 16;
  __shared__ float sA[BK][64 + 4];
  __shared__ float sB[BK][64 + 4];
  const int tid = threadIdx.x;
  const int tx = tid & 15, ty = tid >> 4;
  const int row0 = blockIdx.y * 64, col0 = blockIdx.x * 64;
  const int ar = tid >> 2, ac = (tid & 3) * 4;   // A tile loader: 64x16
  const int br = tid >> 4, bc = (tid & 15) * 4;  // B tile loader: 16x64
  float acc[4][4] = {};
  for (int k0 = 0; k0 < K; k0 += BK) {
    float4 av = *(const float4*)(A + (size_t)(row0 + ar) * K + k0 + ac);
    float4 bv = *(const float4*)(Bw + (size_t)(k0 + br) * N + col0 + bc);
    sA[ac + 0][ar] = av.x;
    sA[ac + 1][ar] = av.y;
    sA[ac + 2][ar] = av.z;
    sA[ac + 3][ar] = av.w;
    *(float4*)&sB[br][bc] = bv;
    __syncthreads();
    #pragma unroll
    for (int kk = 0; kk < BK; ++kk) {
      float4 a = *(const float4*)&sA[kk][ty * 4];
      float4 b = *(const float4*)&sB[kk][tx * 4];
      acc[0][0] += a.x * b.x; acc[0][1] += a.x * b.y; acc[0][2] += a.x * b.z; acc[0][3] += a.x * b.w;
      acc[1][0] += a.y * b.x; acc[1][1] += a.y * b.y; acc[1][2] += a.y * b.z; acc[1][3] += a.y * b.w;
      acc[2][0] += a.z * b.x; acc[2][1] += a.z * b.y; acc[2][2] += a.z * b.z; acc[2][3] += a.z * b.w;
      acc[3][0] += a.w * b.x; acc[3][1] += a.w * b.y; acc[3][2] += a.w * b.z; acc[3][3] += a.w * b.w;
    }
    __syncthreads();
  }
  #pragma unroll
  for (int i = 0; i < 4; ++i) {
    int r = row0 + ty * 4 + i;
    #pragma unroll
    for (int j = 0; j < 4; ++j) {
      int cn = col0 + tx * 4 + j;
      float val = acc[i][j] + bias[cn];
      if (relu) val = fmaxf(val, 0.f);
      if (resid) val += resid[(size_t)r * N + cn];
      Cout[(size_t)r * N + cn] = val;
    }
  }
}

// ---------------------------------------------------------------------------
// Attention: one wave per (query row, head). lane == d (D=64 == wave width).
// Online softmax, causal. q/k/v laid out [M][C] with head offset h*D.
// ---------------------------------------------------------------------------
__global__ __launch_bounds__(64) void attn_kernel(
    const float* __restrict__ qb, const float* __restrict__ kb,
    const float* __restrict__ vb, float* __restrict__ out) {
  const int qi = blockIdx.x;          // b*T + t
  const int h  = blockIdx.y;
  const int b  = qi / T, t = qi % T;
  const int lane = threadIdx.x;
  const size_t base = (size_t)(b * T) * C + h * D + lane;  // row (b, 0)
  const float qd = qb[base + (size_t)t * C] * 0.125f;      // 1/sqrt(64)
  float m = -1e30f, l = 0.f, acc = 0.f;
  for (int kk = 0; kk <= t; ++kk) {
    float s = qd * kb[base + (size_t)kk * C];
    #pragma unroll
    for (int off = 32; off > 0; off >>= 1) s += __shfl_xor(s, off);
    float mn   = fmaxf(m, s);
    float corr = __expf(m - mn);
    float p    = __expf(s - mn);
    l   = l * corr + p;
    acc = acc * corr + p * vb[base + (size_t)kk * C];
    m = mn;
  }
  out[base + (size_t)t * C] = acc / l;
}

// ---------------------------------------------------------------------------
// Logits: out[b, n] = xl[b,:] @ Wout[:, n] + bout[n]; xl staged in LDS.
// Consecutive threads -> consecutive n -> coalesced Wout rows.
// ---------------------------------------------------------------------------
__global__ __launch_bounds__(256) void logits_kernel(
    const float* __restrict__ xl, const float* __restrict__ Wout,
    const float* __restrict__ bout, float* __restrict__ out) {
  __shared__ float sx[B][C];
  for (int i = threadIdx.x; i < B * C; i += 256) sx[i / C][i % C] = xl[i];
  __syncthreads();
  int n = blockIdx.x * 256 + threadIdx.x;
  float acc[B] = {};
  for (int k = 0; k < C; ++k) {
    float w = Wout[(size_t)k * V + n];
    #pragma unroll
    for (int b = 0; b < B; ++b) acc[b] += sx[b][k] * w;
  }
  float bb = bout[n];
  #pragma unroll
  for (int b = 0; b < B; ++b) out[(size_t)b * V + n] = acc[b] + bb;
}

// ---------------------------------------------------------------------------
extern "C" void kernel_launch(void* const* d_in, const int* in_sizes, int n_in,
                              void* d_out, int out_size, void* d_ws, size_t ws_size,
                              hipStream_t stream) {
  const int*   idx     = (const int*)  d_in[0];
  const float* tok_emb = (const float*)d_in[1];
  const float* pos_emb = (const float*)d_in[2];
  const float* Wq   = (const float*)d_in[3];
  const float* bq   = (const float*)d_in[4];
  const float* Wk   = (const float*)d_in[5];
  const float* bk   = (const float*)d_in[6];
  const float* Wv   = (const float*)d_in[7];
  const float* bv   = (const float*)d_in[8];
  const float* Wo   = (const float*)d_in[9];
  const float* bo   = (const float*)d_in[10];
  const float* ln1g = (const float*)d_in[11];
  const float* ln1b = (const float*)d_in[12];
  const float* W1   = (const float*)d_in[13];
  const float* b1   = (const float*)d_in[14];
  const float* W2   = (const float*)d_in[15];
  const float* b2   = (const float*)d_in[16];
  const float* ln2g = (const float*)d_in[17];
  const float* ln2b = (const float*)d_in[18];
  const float* lnfg = (const float*)d_in[19];
  const float* lnfb = (const float*)d_in[20];
  const float* Wout = (const float*)d_in[21];
  const float* bout = (const float*)d_in[22];
  float* out = (float*)d_out;

  float* ws = (float*)d_ws;
  const size_t MC = (size_t)M * C;   // 8.39M floats
  float* x  = ws;
  float* h  = x  + MC;
  float* qb = h  + MC;
  float* kb = qb + MC;
  float* vb = kb + MC;
  float* fb = vb + MC;               // M*F
  float* xl = fb + (size_t)M * F;    // B*C

  // 1. Embedding
  embed_kernel<<<(M * C) / 1024, 256, 0, stream>>>(idx, tok_emb, pos_emb, x);

  const dim3 gC(C / 64, M / 64);   // N=1024 GEMMs
  const dim3 gF(F / 64, M / 64);   // N=4096 GEMM

  for (int l = 0; l < L; ++l) {
    const float* wq = Wq + (size_t)l * C * C;
    const float* wk = Wk + (size_t)l * C * C;
    const float* wv = Wv + (size_t)l * C * C;
    const float* wo = Wo + (size_t)l * C * C;
    const float* w1 = W1 + (size_t)l * C * F;
    const float* w2 = W2 + (size_t)l * F * C;

    // LN1
    ln_kernel<<<M, 256, 0, stream>>>(x, ln1g + l * C, ln1b + l * C, h, 1, 0);
    // QKV projections
    gemm_kernel<<<gC, 256, 0, stream>>>(h, wq, bq + l * C, nullptr, qb, C, C, 0);
    gemm_kernel<<<gC, 256, 0, stream>>>(h, wk, bk + l * C, nullptr, kb, C, C, 0);
    gemm_kernel<<<gC, 256, 0, stream>>>(h, wv, bv + l * C, nullptr, vb, C, C, 0);
    // Attention (writes into h, reused as attn-out buffer)
    attn_kernel<<<dim3(B * T, H), 64, 0, stream>>>(qb, kb, vb, h);
    // Output projection + residual into x
    gemm_kernel<<<gC, 256, 0, stream>>>(h, wo, bo + l * C, x, x, C, C, 0);
    // LN2
    ln_kernel<<<M, 256, 0, stream>>>(x, ln2g + l * C, ln2b + l * C, h, 1, 0);
    // FFN
    gemm_kernel<<<gF, 256, 0, stream>>>(h, w1, b1 + l * F, nullptr, fb, F, C, 1);
    gemm_kernel<<<gC, 256, 0, stream>>>(fb, w2, b2 + l * C, x, x, C, F, 0);
  }

  // Final LN on last position only (reference LNs everything then slices [-1])
  ln_kernel<<<B, 256, 0, stream>>>(x, lnfg, lnfb, xl, T, T - 1);
  // Logits
  logits_kernel<<<V / 256, 256, 0, stream>>>(xl, Wout, bout, out);
}

// Round 2
// 18060.281 us; speedup vs baseline: 2.6640x; 2.6640x over previous
//
#include <hip/hip_runtime.h>
#include <hip/hip_bf16.h>
#include <math.h>

// Problem constants (from reference)
constexpr int L = 4, B = 4, T = 2048, C = 1024, H = 16, F = 4096, V = 32000;
constexpr int D = C / H;        // 64
constexpr int M = B * T;        // 8192 token rows
constexpr float EPS = 1e-5f;

// ---------------------------------------------------------------------------
// Embedding: x[b,t,:] = tok_emb[idx[b,t],:] + pos_emb[t,:]
// ---------------------------------------------------------------------------
__global__ __launch_bounds__(256) void embed_kernel(
    const int* __restrict__ idx, const float* __restrict__ tok,
    const float* __restrict__ pos, float* __restrict__ x) {
  size_t e4 = ((size_t)blockIdx.x * 256 + threadIdx.x) * 4;  // float index
  int row = (int)(e4 / C);
  int c   = (int)(e4 % C);
  int t   = row % T;
  int tokid = idx[row];
  const float4 tv = *(const float4*)(tok + (size_t)tokid * C + c);
  const float4 pv = *(const float4*)(pos + (size_t)t * C + c);
  float4 o;
  o.x = tv.x + pv.x; o.y = tv.y + pv.y; o.z = tv.z + pv.z; o.w = tv.w + pv.w;
  *(float4*)(x + e4) = o;
}

// ---------------------------------------------------------------------------
// LayerNorm: one 256-thread block per row (C=1024 -> 4 elems/thread).
// in-row = blockIdx.x*rowMul + rowAdd ; out-row = blockIdx.x (compact).
// ---------------------------------------------------------------------------
__global__ __launch_bounds__(256) void ln_kernel(
    const float* __restrict__ xin, const float* __restrict__ g,
    const float* __restrict__ bta, float* __restrict__ out,
    int rowMul, int rowAdd) {
  int row_in = blockIdx.x * rowMul + rowAdd;
  const float* xr = xin + (size_t)row_in * C;
  int c = threadIdx.x * 4;
  float4 xv = *(const float4*)(xr + c);
  float s  = xv.x + xv.y + xv.z + xv.w;
  float ss = xv.x * xv.x + xv.y * xv.y + xv.z * xv.z + xv.w * xv.w;
  #pragma unroll
  for (int off = 32; off > 0; off >>= 1) {
    s  += __shfl_xor(s, off);
    ss += __shfl_xor(ss, off);
  }
  __shared__ float sh[8];
  int wid = threadIdx.x >> 6, lane = threadIdx.x & 63;
  if (lane == 0) { sh[wid * 2] = s; sh[wid * 2 + 1] = ss; }
  __syncthreads();
  s  = sh[0] + sh[2] + sh[4] + sh[6];
  ss = sh[1] + sh[3] + sh[5] + sh[7];
  float mean = s / C;
  float var  = ss / C - mean * mean;
  float inv  = rsqrtf(var + EPS);
  float4 gv = *(const float4*)(g + c);
  float4 bv = *(const float4*)(bta + c);
  float4 o;
  o.x = (xv.x - mean) * inv * gv.x + bv.x;
  o.y = (xv.y - mean) * inv * gv.y + bv.y;
  o.z = (xv.z - mean) * inv * gv.z + bv.z;
  o.w = (xv.w - mean) * inv * gv.w + bv.w;
  *(float4*)(out + (size_t)blockIdx.x * C + c) = o;
}

// ---------------------------------------------------------------------------
// fp32 tiled GEMM: Cout[M x N] = A[M x K] @ Bw[K x N] + bias (+resid) (relu?)
// 64x64 tile, 256 threads (16x16), 4x4 acc per thread, BK=16.
// ---------------------------------------------------------------------------
__global__ __launch_bounds__(256) void gemm_kernel(
    const float* __restrict__ A, const float* __restrict__ Bw,
    const float* __restrict__ bias, const float* __restrict__ resid,
    float* __restrict__ Cout, int N, int K, int relu) {
  constexpr int BK = 16;
  __shared__ float sA[BK][64 + 4];
  __shared__ float sB[BK][64 + 4];
  const int tid = threadIdx.x;
  const int tx = tid & 15, ty = tid >> 4;
  const int row0 = blockIdx.y * 64, col0 = blockIdx.x * 64;
  const int ar = tid >> 2, ac = (tid & 3) * 4;   // A tile loader: 64x16
  const int br = tid >> 4, bc = (tid & 15) * 4;  // B tile loader: 16x64
  float acc[4][4] = {};
  for (int k0 = 0; k0 < K; k0 += BK) {
    float4 av = *(const float4*)(A + (size_t)(row0 + ar) * K + k0 + ac);
    float4 bv = *(const float4*)(Bw + (size_t)(k0 + br) * N + col0 + bc);
    sA[ac + 0][ar] = av.x;
    sA[ac + 1][ar] = av.y;
    sA[ac + 2][ar] = av.z;
    sA[ac + 3][ar] = av.w;
    *(float4*)&sB[br][bc] = bv;
    __syncthreads();
    #pragma unroll
    for (int kk = 0; kk < BK; ++kk) {
      float4 a = *(const float4*)&sA[kk][ty * 4];
      float4 b = *(const float4*)&sB[kk][tx * 4];
      acc[0][0] += a.x * b.x; acc[0][1] += a.x * b.y; acc[0][2] += a.x * b.z; acc[0][3] += a.x * b.w;
      acc[1][0] += a.y * b.x; acc[1][1] += a.y * b.y; acc[1][2] += a.y * b.z; acc[1][3] += a.y * b.w;
      acc[2][0] += a.z * b.x; acc[2][1] += a.z * b.y; acc[2][2] += a.z * b.z; acc[2][3] += a.z * b.w;
      acc[3][0] += a.w * b.x; acc[3][1] += a.w * b.y; acc[3][2] += a.w * b.z; acc[3][3] += a.w * b.w;
    }
    __syncthreads();
  }
  #pragma unroll
  for (int i = 0; i < 4; ++i) {
    int r = row0 + ty * 4 + i;
    #pragma unroll
    for (int j = 0; j < 4; ++j) {
      int cn = col0 + tx * 4 + j;
      float val = acc[i][j] + bias[cn];
      if (relu) val = fmaxf(val, 0.f);
      if (resid) val += resid[(size_t)r * N + cn];
      Cout[(size_t)r * N + cn] = val;
    }
  }
}

// ---------------------------------------------------------------------------
// Flash attention (fp32 vector): thread-per-query, K/V tiles in LDS.
// Block = 256 threads = 256 consecutive query rows of one (b, h).
// Grid = (M/256, H). Online softmax in registers; q & acc in VGPRs.
// LDS broadcast: all lanes read the same K/V row in lockstep (conflict-free).
// ---------------------------------------------------------------------------
constexpr int TK = 64;  // k-tile
__global__ __launch_bounds__(256) void flash_attn_kernel(
    const float* __restrict__ qb, const float* __restrict__ kb,
    const float* __restrict__ vb, float* __restrict__ out) {
  const int h   = blockIdx.y;
  const int tid = threadIdx.x;
  const int row = blockIdx.x * 256 + tid;   // global query row (b*T + t)
  const int b   = row / T, t = row % T;     // block sits entirely in one b
  const int t0  = (blockIdx.x * 256) % T;

  __shared__ float sK[TK][D];
  __shared__ float sV[TK][D];

  // q row -> registers, pre-scaled by 1/sqrt(D)=0.125
  const float* qr = qb + (size_t)row * C + h * D;
  float4 q[16];
  #pragma unroll
  for (int i = 0; i < 16; ++i) {
    q[i] = ((const float4*)qr)[i];
    q[i].x *= 0.125f; q[i].y *= 0.125f; q[i].z *= 0.125f; q[i].w *= 0.125f;
  }

  float4 acc[16] = {};
  float m = -1e30f, lsum = 0.f;

  const int tmax = t0 + 255;                       // last t in this block
  const size_t kvbase = (size_t)(b * T) * C + h * D;

  for (int k0 = 0; k0 <= tmax; k0 += TK) {
    // cooperative K/V tile load: TK x D floats each, coalesced
    {
      const int r  = tid >> 4;          // 0..15
      const int c4 = (tid & 15) * 4;
      #pragma unroll
      for (int rr = 0; rr < TK; rr += 16) {
        const size_t g = kvbase + (size_t)(k0 + r + rr) * C + c4;
        *(float4*)&sK[r + rr][c4] = *(const float4*)(kb + g);
        *(float4*)&sV[r + rr][c4] = *(const float4*)(vb + g);
      }
    }
    __syncthreads();

    int lim = t - k0 + 1;                // per-thread causal limit
    if (lim > TK) lim = TK;
    for (int kk = 0; kk < lim; ++kk) {
      float s = 0.f;
      #pragma unroll
      for (int i = 0; i < 16; ++i) {
        float4 kv = *(const float4*)&sK[kk][i * 4];
        s += q[i].x * kv.x + q[i].y * kv.y + q[i].z * kv.z + q[i].w * kv.w;
      }
      float mn   = fmaxf(m, s);
      float corr = __expf(m - mn);
      float p    = __expf(s - mn);
      lsum = lsum * corr + p;
      m = mn;
      #pragma unroll
      for (int i = 0; i < 16; ++i) {
        float4 vv = *(const float4*)&sV[kk][i * 4];
        acc[i].x = acc[i].x * corr + p * vv.x;
        acc[i].y = acc[i].y * corr + p * vv.y;
        acc[i].z = acc[i].z * corr + p * vv.z;
        acc[i].w = acc[i].w * corr + p * vv.w;
      }
    }
    __syncthreads();
  }

  const float inv = 1.f / lsum;
  float* orow = out + (size_t)row * C + h * D;
  #pragma unroll
  for (int i = 0; i < 16; ++i) {
    float4 o;
    o.x = acc[i].x * inv; o.y = acc[i].y * inv;
    o.z = acc[i].z * inv; o.w = acc[i].w * inv;
    ((float4*)orow)[i] = o;
  }
}

// ---------------------------------------------------------------------------
// Logits: out[b, n] = xl[b,:] @ Wout[:, n] + bout[n]; xl staged in LDS.
// ---------------------------------------------------------------------------
__global__ __launch_bounds__(256) void logits_kernel(
    const float* __restrict__ xl, const float* __restrict__ Wout,
    const float* __restrict__ bout, float* __restrict__ out) {
  __shared__ float sx[B][C];
  for (int i = threadIdx.x; i < B * C; i += 256) sx[i / C][i % C] = xl[i];
  __syncthreads();
  int n = blockIdx.x * 256 + threadIdx.x;
  float acc[B] = {};
  for (int k = 0; k < C; ++k) {
    float w = Wout[(size_t)k * V + n];
    #pragma unroll
    for (int b = 0; b < B; ++b) acc[b] += sx[b][k] * w;
  }
  float bb = bout[n];
  #pragma unroll
  for (int b = 0; b < B; ++b) out[(size_t)b * V + n] = acc[b] + bb;
}

// ---------------------------------------------------------------------------
extern "C" void kernel_launch(void* const* d_in, const int* in_sizes, int n_in,
                              void* d_out, int out_size, void* d_ws, size_t ws_size,
                              hipStream_t stream) {
  const int*   idx     = (const int*)  d_in[0];
  const float* tok_emb = (const float*)d_in[1];
  const float* pos_emb = (const float*)d_in[2];
  const float* Wq   = (const float*)d_in[3];
  const float* bq   = (const float*)d_in[4];
  const float* Wk   = (const float*)d_in[5];
  const float* bk   = (const float*)d_in[6];
  const float* Wv   = (const float*)d_in[7];
  const float* bv   = (const float*)d_in[8];
  const float* Wo   = (const float*)d_in[9];
  const float* bo   = (const float*)d_in[10];
  const float* ln1g = (const float*)d_in[11];
  const float* ln1b = (const float*)d_in[12];
  const float* W1   = (const float*)d_in[13];
  const float* b1   = (const float*)d_in[14];
  const float* W2   = (const float*)d_in[15];
  const float* b2   = (const float*)d_in[16];
  const float* ln2g = (const float*)d_in[17];
  const float* ln2b = (const float*)d_in[18];
  const float* lnfg = (const float*)d_in[19];
  const float* lnfb = (const float*)d_in[20];
  const float* Wout = (const float*)d_in[21];
  const float* bout = (const float*)d_in[22];
  float* out = (float*)d_out;

  float* ws = (float*)d_ws;
  const size_t MC = (size_t)M * C;
  float* x  = ws;
  float* h  = x  + MC;
  float* qb = h  + MC;
  float* kb = qb + MC;
  float* vb = kb + MC;
  float* fb = vb + MC;               // M*F
  float* xl = fb + (size_t)M * F;    // B*C

  embed_kernel<<<(M * C) / 1024, 256, 0, stream>>>(idx, tok_emb, pos_emb, x);

  const dim3 gC(C / 64, M / 64);
  const dim3 gF(F / 64, M / 64);

  for (int l = 0; l < L; ++l) {
    const float* wq = Wq + (size_t)l * C * C;
    const float* wk = Wk + (size_t)l * C * C;
    const float* wv = Wv + (size_t)l * C * C;
    const float* wo = Wo + (size_t)l * C * C;
    const float* w1 = W1 + (size_t)l * C * F;
    const float* w2 = W2 + (size_t)l * F * C;

    ln_kernel<<<M, 256, 0, stream>>>(x, ln1g + l * C, ln1b + l * C, h, 1, 0);
    gemm_kernel<<<gC, 256, 0, stream>>>(h, wq, bq + l * C, nullptr, qb, C, C, 0);
    gemm_kernel<<<gC, 256, 0, stream>>>(h, wk, bk + l * C, nullptr, kb, C, C, 0);
    gemm_kernel<<<gC, 256, 0, stream>>>(h, wv, bv + l * C, nullptr, vb, C, C, 0);
    flash_attn_kernel<<<dim3(M / 256, H), 256, 0, stream>>>(qb, kb, vb, h);
    gemm_kernel<<<gC, 256, 0, stream>>>(h, wo, bo + l * C, x, x, C, C, 0);
    ln_kernel<<<M, 256, 0, stream>>>(x, ln2g + l * C, ln2b + l * C, h, 1, 0);
    gemm_kernel<<<gF, 256, 0, stream>>>(h, w1, b1 + l * F, nullptr, fb, F, C, 1);
    gemm_kernel<<<gC, 256, 0, stream>>>(fb, w2, b2 + l * C, x, x, C, F, 0);
  }

  ln_kernel<<<B, 256, 0, stream>>>(x, lnfg, lnfb, xl, T, T - 1);
  logits_kernel<<<V / 256, 256, 0, stream>>>(xl, Wout, bout, out);
}